// Round 1
// baseline (919.886 us; speedup 1.0000x reference)
//
#include <hip/hip_runtime.h>
#include <hip/hip_bf16.h>
#include <math.h>

#define NROWS 8192
#define DIM   256
#define INV_T 14.285714285714286f   // 1/0.07
#define EPS_N 1e-8f

#define BI 32
#define BJ 64

// ---------------------------------------------------------------------------
// Kernel 1: per-row inverse norms for u and v, plus diag logit
//   invu[r] = 1/max(||u_r||, eps); invv likewise
//   diag[r] = <u_r, v_r> * invu[r] * invv[r] / T
// One wave per row (4 waves/block). lane l covers elements 4l..4l+3.
// ---------------------------------------------------------------------------
__global__ __launch_bounds__(256) void norms_kernel(
    const float* __restrict__ u, const float* __restrict__ v,
    float* __restrict__ invu, float* __restrict__ invv,
    float* __restrict__ diag)
{
    const int wid  = threadIdx.x >> 6;
    const int lane = threadIdx.x & 63;
    const int r    = blockIdx.x * 4 + wid;

    const float4* u4 = (const float4*)(u + (size_t)r * DIM);
    const float4* v4 = (const float4*)(v + (size_t)r * DIM);
    float4 a = u4[lane];
    float4 b = v4[lane];

    float ssu = a.x * a.x + a.y * a.y + a.z * a.z + a.w * a.w;
    float ssv = b.x * b.x + b.y * b.y + b.z * b.z + b.w * b.w;
    float duv = a.x * b.x + a.y * b.y + a.z * b.z + a.w * b.w;

    #pragma unroll
    for (int m = 32; m >= 1; m >>= 1) {
        ssu += __shfl_xor(ssu, m);
        ssv += __shfl_xor(ssv, m);
        duv += __shfl_xor(duv, m);
    }

    if (lane == 0) {
        float iu = 1.0f / fmaxf(sqrtf(ssu), EPS_N);
        float iv = 1.0f / fmaxf(sqrtf(ssv), EPS_N);
        invu[r] = iu;
        invv[r] = iv;
        diag[r] = duv * iu * iv * INV_T;
    }
}

// ---------------------------------------------------------------------------
// Kernel 2: block b owns rows i0=b*32..i0+31. Loops over all j in tiles of 64.
// LDS: uT[d][r] (normalized u, transposed, stride 34 => conflict-free b64),
//      vT[d][c] (normalized v tile, transposed => b128 broadcast reads).
// Thread (ti=t&15, tj=t>>4) computes rows {2ti,2ti+1} x cols {4tj..4tj+3}.
// Each thread accumulates sum_j exp(cos_ij/T) for its j-subset; LDS reduce at
// the end, lse = log(sum), contrib = lse - diag, atomicAdd(mean contribution).
// ---------------------------------------------------------------------------
__global__ __launch_bounds__(256) void infonce_kernel(
    const float* __restrict__ u, const float* __restrict__ v,
    const float* __restrict__ invu, const float* __restrict__ invv,
    const float* __restrict__ diag, float* __restrict__ out)
{
    __shared__ float uT[DIM][BI + 2];   // [d][r], stride 34 (even -> b64 ok)
    __shared__ float vT[DIM][BJ];       // [d][c]
    __shared__ float red[BI][17];

    const int t  = threadIdx.x;
    const int i0 = blockIdx.x * BI;

    // ---- stage u: 32 rows x 256, normalized, transposed ----
    {
        const int r = t >> 3;          // 0..31
        const int q = t & 7;           // 0..7
        const float sc = invu[i0 + r];
        const float4* up = (const float4*)(u + (size_t)(i0 + r) * DIM);
        #pragma unroll
        for (int it = 0; it < 8; ++it) {
            const int d4 = q + (it << 3);     // 0..63
            float4 x = up[d4];
            uT[4 * d4 + 0][r] = x.x * sc;
            uT[4 * d4 + 1][r] = x.y * sc;
            uT[4 * d4 + 2][r] = x.z * sc;
            uT[4 * d4 + 3][r] = x.w * sc;
        }
    }

    const int ti = t & 15;
    const int tj = t >> 4;
    const int cs = t >> 2;             // 0..63 : v-staging row
    const int qs = t & 3;              // 0..3

    float sume0 = 0.0f, sume1 = 0.0f;

    for (int jt = 0; jt < NROWS; jt += BJ) {
        // ---- stage v tile: 64 rows x 256, normalized, transposed ----
        const float sc = invv[jt + cs];
        const float4* vp = (const float4*)(v + (size_t)(jt + cs) * DIM);
        __syncthreads();               // previous tile's readers done
        #pragma unroll
        for (int it = 0; it < 16; ++it) {
            const int d4 = qs + (it << 2);    // 0..63
            float4 x = vp[d4];
            vT[4 * d4 + 0][cs] = x.x * sc;
            vT[4 * d4 + 1][cs] = x.y * sc;
            vT[4 * d4 + 2][cs] = x.z * sc;
            vT[4 * d4 + 3][cs] = x.w * sc;
        }
        __syncthreads();

        // ---- 2x4 register tile over d ----
        float acc00 = 0.f, acc01 = 0.f, acc02 = 0.f, acc03 = 0.f;
        float acc10 = 0.f, acc11 = 0.f, acc12 = 0.f, acc13 = 0.f;
        #pragma unroll 8
        for (int d = 0; d < DIM; ++d) {
            const float2 uu = *(const float2*)&uT[d][2 * ti];
            const float4 vv = *(const float4*)&vT[d][4 * tj];
            acc00 += uu.x * vv.x; acc01 += uu.x * vv.y;
            acc02 += uu.x * vv.z; acc03 += uu.x * vv.w;
            acc10 += uu.y * vv.x; acc11 += uu.y * vv.y;
            acc12 += uu.y * vv.z; acc13 += uu.y * vv.w;
        }
        sume0 += __expf(acc00 * INV_T) + __expf(acc01 * INV_T)
               + __expf(acc02 * INV_T) + __expf(acc03 * INV_T);
        sume1 += __expf(acc10 * INV_T) + __expf(acc11 * INV_T)
               + __expf(acc12 * INV_T) + __expf(acc13 * INV_T);
    }

    // ---- per-row reduce across the 16 tj partitions ----
    __syncthreads();
    red[2 * ti + 0][tj] = sume0;
    red[2 * ti + 1][tj] = sume1;
    __syncthreads();

    if (t < BI) {
        float s = 0.0f;
        #pragma unroll
        for (int k = 0; k < 16; ++k) s += red[t][k];
        float c = logf(s) - diag[i0 + t];
        #pragma unroll
        for (int m = 16; m >= 1; m >>= 1) c += __shfl_xor(c, m);
        if (t == 0) atomicAdd(out, c * (1.0f / (float)NROWS));
    }
}

// ---------------------------------------------------------------------------
extern "C" void kernel_launch(void* const* d_in, const int* in_sizes, int n_in,
                              void* d_out, int out_size, void* d_ws, size_t ws_size,
                              hipStream_t stream)
{
    const float* u = (const float*)d_in[0];
    const float* v = (const float*)d_in[1];
    float* out = (float*)d_out;

    float* wsf  = (float*)d_ws;
    float* invu = wsf;
    float* invv = wsf + NROWS;
    float* diag = wsf + 2 * NROWS;

    hipMemsetAsync(out, 0, sizeof(float), stream);

    norms_kernel<<<NROWS / 4, 256, 0, stream>>>(u, v, invu, invv, diag);
    infonce_kernel<<<NROWS / BI, 256, 0, stream>>>(u, v, invu, invv, diag, out);
}

// Round 2
// 137.497 us; speedup vs baseline: 6.6902x; 6.6902x over previous
//
#include <hip/hip_runtime.h>
#include <hip/hip_bf16.h>
#include <math.h>

#define NROWS 8192
#define DIM   256
#define INV_T 14.285714285714286f   // 1/0.07
#define EPS_N 1e-8f

#define BM 128
#define BN 128
#define BK 64

typedef __attribute__((ext_vector_type(8))) short short8;
typedef __attribute__((ext_vector_type(4))) float f32x4;

typedef const __attribute__((address_space(1))) void g_void;
typedef __attribute__((address_space(3))) void l_void;

__device__ inline unsigned short f2bf(float x) {
    __hip_bfloat16 h = __float2bfloat16(x);
    return __builtin_bit_cast(unsigned short, h);
}

// ---------------------------------------------------------------------------
// Kernel 1: per-row normalize u,v -> bf16 un,vn ; diag logit in fp32.
// One wave per row, lane l holds elements 4l..4l+3.
// ---------------------------------------------------------------------------
__global__ __launch_bounds__(256) void norm_kernel(
    const float* __restrict__ u, const float* __restrict__ v,
    unsigned short* __restrict__ un, unsigned short* __restrict__ vn,
    float* __restrict__ diag)
{
    const int wid  = threadIdx.x >> 6;
    const int lane = threadIdx.x & 63;
    const int r    = blockIdx.x * 4 + wid;

    const float4* u4 = (const float4*)(u + (size_t)r * DIM);
    const float4* v4 = (const float4*)(v + (size_t)r * DIM);
    float4 a = u4[lane];
    float4 b = v4[lane];

    float ssu = a.x * a.x + a.y * a.y + a.z * a.z + a.w * a.w;
    float ssv = b.x * b.x + b.y * b.y + b.z * b.z + b.w * b.w;
    float duv = a.x * b.x + a.y * b.y + a.z * b.z + a.w * b.w;

    #pragma unroll
    for (int m = 32; m >= 1; m >>= 1) {
        ssu += __shfl_xor(ssu, m);
        ssv += __shfl_xor(ssv, m);
        duv += __shfl_xor(duv, m);
    }

    const float iu = 1.0f / fmaxf(sqrtf(ssu), EPS_N);
    const float iv = 1.0f / fmaxf(sqrtf(ssv), EPS_N);

    ushort4 pu, pv;
    pu.x = f2bf(a.x * iu); pu.y = f2bf(a.y * iu);
    pu.z = f2bf(a.z * iu); pu.w = f2bf(a.w * iu);
    pv.x = f2bf(b.x * iv); pv.y = f2bf(b.y * iv);
    pv.z = f2bf(b.z * iv); pv.w = f2bf(b.w * iv);
    *(ushort4*)(un + (size_t)r * DIM + 4 * lane) = pu;
    *(ushort4*)(vn + (size_t)r * DIM + 4 * lane) = pv;

    if (lane == 0) diag[r] = duv * iu * iv * INV_T;
}

// ---------------------------------------------------------------------------
// Kernel 2: 128x128 output tile per block (m97 structure), K=256 in 4 steps.
// 4 waves in 2x2; per-wave 64x64 = 4x4 frags of 16x16x32 bf16 MFMA.
// Epilogue: exp(acc/T... acc*INV_T), reduce cols, atomicAdd rowsum.
// ---------------------------------------------------------------------------
__global__ __launch_bounds__(256) void gemm_kernel(
    const unsigned short* __restrict__ un, const unsigned short* __restrict__ vn,
    float* __restrict__ rowsum)
{
    __shared__ unsigned short As[2][BM][BK];   // 32 KB
    __shared__ unsigned short Bs[2][BN][BK];   // 32 KB

    const int t    = threadIdx.x;
    const int lane = t & 63;
    const int wid  = t >> 6;
    const int wr   = wid >> 1;
    const int wc   = wid & 1;
    const int i0   = blockIdx.x * BM;
    const int j0   = blockIdx.y * BN;

    // --- staging: each wave loads 32 rows of A and 32 rows of B per K-step ---
    auto stage = [&](int buf, int kt) {
        const int k0 = kt * BK;
        #pragma unroll
        for (int s = 0; s < 4; ++s) {
            const int rbase = wid * 32 + s * 8;
            const int r = rbase + (lane >> 3);
            const unsigned short* ga =
                un + (size_t)(i0 + r) * DIM + k0 + (lane & 7) * 8;
            __builtin_amdgcn_global_load_lds((g_void*)ga,
                (l_void*)&As[buf][rbase][0], 16, 0, 0);
            const unsigned short* gb =
                vn + (size_t)(j0 + r) * DIM + k0 + (lane & 7) * 8;
            __builtin_amdgcn_global_load_lds((g_void*)gb,
                (l_void*)&Bs[buf][rbase][0], 16, 0, 0);
        }
    };

    f32x4 acc[4][4] = {};

    stage(0, 0);
    __syncthreads();

    int buf = 0;
    #pragma unroll
    for (int kt = 0; kt < 4; ++kt) {
        if (kt < 3) stage(buf ^ 1, kt + 1);
        #pragma unroll
        for (int kk = 0; kk < 2; ++kk) {
            short8 av[4], bv[4];
            #pragma unroll
            for (int m = 0; m < 4; ++m)
                av[m] = *(const short8*)
                    &As[buf][wr * 64 + m * 16 + (lane & 15)][kk * 32 + (lane >> 4) * 8];
            #pragma unroll
            for (int n = 0; n < 4; ++n)
                bv[n] = *(const short8*)
                    &Bs[buf][wc * 64 + n * 16 + (lane & 15)][kk * 32 + (lane >> 4) * 8];
            #pragma unroll
            for (int m = 0; m < 4; ++m)
                #pragma unroll
                for (int n = 0; n < 4; ++n)
                    acc[m][n] = __builtin_amdgcn_mfma_f32_16x16x32_bf16(
                        av[m], bv[n], acc[m][n], 0, 0, 0);
        }
        __syncthreads();
        buf ^= 1;
    }

    // --- epilogue: exp + row-sum. C/D: col = lane&15, row = (lane>>4)*4+reg ---
    #pragma unroll
    for (int m = 0; m < 4; ++m) {
        float p0 = 0.f, p1 = 0.f, p2 = 0.f, p3 = 0.f;
        #pragma unroll
        for (int n = 0; n < 4; ++n) {
            p0 += __expf(acc[m][n][0] * INV_T);
            p1 += __expf(acc[m][n][1] * INV_T);
            p2 += __expf(acc[m][n][2] * INV_T);
            p3 += __expf(acc[m][n][3] * INV_T);
        }
        #pragma unroll
        for (int msk = 1; msk < 16; msk <<= 1) {
            p0 += __shfl_xor(p0, msk);
            p1 += __shfl_xor(p1, msk);
            p2 += __shfl_xor(p2, msk);
            p3 += __shfl_xor(p3, msk);
        }
        if ((lane & 15) == 0) {
            const int rb = i0 + wr * 64 + m * 16 + (lane >> 4) * 4;
            atomicAdd(&rowsum[rb + 0], p0);
            atomicAdd(&rowsum[rb + 1], p1);
            atomicAdd(&rowsum[rb + 2], p2);
            atomicAdd(&rowsum[rb + 3], p3);
        }
    }
}

// ---------------------------------------------------------------------------
// Kernel 3: out = mean(log(rowsum) - diag)
// ---------------------------------------------------------------------------
__global__ __launch_bounds__(256) void finish_kernel(
    const float* __restrict__ rowsum, const float* __restrict__ diag,
    float* __restrict__ out)
{
    __shared__ float red[4];
    const int r    = blockIdx.x * 256 + threadIdx.x;
    const int lane = threadIdx.x & 63;
    const int wid  = threadIdx.x >> 6;

    float c = logf(rowsum[r]) - diag[r];
    #pragma unroll
    for (int m = 32; m >= 1; m >>= 1) c += __shfl_xor(c, m);
    if (lane == 0) red[wid] = c;
    __syncthreads();
    if (threadIdx.x == 0) {
        float s = red[0] + red[1] + red[2] + red[3];
        atomicAdd(out, s * (1.0f / (float)NROWS));
    }
}

// ---------------------------------------------------------------------------
extern "C" void kernel_launch(void* const* d_in, const int* in_sizes, int n_in,
                              void* d_out, int out_size, void* d_ws, size_t ws_size,
                              hipStream_t stream)
{
    const float* u = (const float*)d_in[0];
    const float* v = (const float*)d_in[1];
    float* out = (float*)d_out;

    char* w = (char*)d_ws;
    unsigned short* un = (unsigned short*)w;                                  // 4 MB
    unsigned short* vn = (unsigned short*)(w + (size_t)NROWS * DIM * 2);      // 4 MB
    float* diag   = (float*)(w + (size_t)NROWS * DIM * 4);                    // 32 KB
    float* rowsum = diag + NROWS;                                             // 32 KB

    hipMemsetAsync(out, 0, sizeof(float), stream);
    hipMemsetAsync(rowsum, 0, NROWS * sizeof(float), stream);

    norm_kernel<<<NROWS / 4, 256, 0, stream>>>(u, v, un, vn, diag);
    gemm_kernel<<<dim3(64, 64), 256, 0, stream>>>(un, vn, rowsum);
    finish_kernel<<<NROWS / 256, 256, 0, stream>>>(rowsum, diag, out);
}

// Round 3
// 118.976 us; speedup vs baseline: 7.7317x; 1.1557x over previous
//
#include <hip/hip_runtime.h>
#include <hip/hip_bf16.h>
#include <math.h>

#define NROWS 8192
#define DIM   256
#define INV_T 14.285714285714286f   // 1/0.07
#define EPS_N 1e-8f

typedef __attribute__((ext_vector_type(8))) short short8;
typedef __attribute__((ext_vector_type(4))) float f32x4;

typedef const __attribute__((address_space(1))) void g_void;
typedef __attribute__((address_space(3))) void l_void;

__device__ inline unsigned short f2bf(float x) {
    __hip_bfloat16 h = __float2bfloat16(x);
    return __builtin_bit_cast(unsigned short, h);
}

// ---------------------------------------------------------------------------
// Kernel 1: per-row normalize u,v -> bf16 un,vn ; diag logit fp32; zero rowsum.
// ---------------------------------------------------------------------------
__global__ __launch_bounds__(256) void norm_kernel(
    const float* __restrict__ u, const float* __restrict__ v,
    unsigned short* __restrict__ un, unsigned short* __restrict__ vn,
    float* __restrict__ diag, float* __restrict__ rowsum)
{
    if (threadIdx.x < 4) rowsum[blockIdx.x * 4 + threadIdx.x] = 0.0f;

    const int wid  = threadIdx.x >> 6;
    const int lane = threadIdx.x & 63;
    const int r    = blockIdx.x * 4 + wid;

    const float4* u4 = (const float4*)(u + (size_t)r * DIM);
    const float4* v4 = (const float4*)(v + (size_t)r * DIM);
    float4 a = u4[lane];
    float4 b = v4[lane];

    float ssu = a.x * a.x + a.y * a.y + a.z * a.z + a.w * a.w;
    float ssv = b.x * b.x + b.y * b.y + b.z * b.z + b.w * b.w;
    float duv = a.x * b.x + a.y * b.y + a.z * b.z + a.w * b.w;

    #pragma unroll
    for (int m = 32; m >= 1; m >>= 1) {
        ssu += __shfl_xor(ssu, m);
        ssv += __shfl_xor(ssv, m);
        duv += __shfl_xor(duv, m);
    }

    const float iu = 1.0f / fmaxf(sqrtf(ssu), EPS_N);
    const float iv = 1.0f / fmaxf(sqrtf(ssv), EPS_N);

    ushort4 pu, pv;
    pu.x = f2bf(a.x * iu); pu.y = f2bf(a.y * iu);
    pu.z = f2bf(a.z * iu); pu.w = f2bf(a.w * iu);
    pv.x = f2bf(b.x * iv); pv.y = f2bf(b.y * iv);
    pv.z = f2bf(b.z * iv); pv.w = f2bf(b.w * iv);
    *(ushort4*)(un + (size_t)r * DIM + 4 * lane) = pu;
    *(ushort4*)(vn + (size_t)r * DIM + 4 * lane) = pv;

    if (lane == 0) diag[r] = duv * iu * iv * INV_T;
}

// ---------------------------------------------------------------------------
// Kernel 2: flash-style. Block = 128 i-rows x 1024 j-cols (16 tiles of 64).
// A-frags in registers (full K=256). B j-tile staged in LDS, k-chunk layout
// Bs[kg][row][8] via per-lane-source-permuted global_load_lds (conflict-free
// ds_read_b128). 4 waves 2x2; per wave per j-step: 16 b128 + 64 MFMA.
// exp accumulated into register row-sums; one reduce+atomic per block.
// ---------------------------------------------------------------------------
__global__ __launch_bounds__(256, 2) void gemm_kernel(
    const unsigned short* __restrict__ un, const unsigned short* __restrict__ vn,
    float* __restrict__ rowsum)
{
    __shared__ unsigned short Bs[2][32][64][8];   // 64 KB

    const int t    = threadIdx.x;
    const int lane = t & 63;
    const int wid  = t >> 6;
    const int wr   = wid >> 1;
    const int wc   = wid & 1;
    const int bid  = blockIdx.x;
    const int by   = bid & 7;          // XCD id -> j-panel pinned to one L2
    const int bx   = bid >> 3;
    const int i0   = bx * 128;
    const int j0   = by * 1024;

    const int lr = lane & 15;          // frag row (A) / frag col (B, C/D)
    const int lg = lane >> 4;          // k-group

    // ---- A fragments: rows i0+wr*64+m*16+lr, k = k*32 + lg*8 .. +7 ----
    short8 av[4][8];
    #pragma unroll
    for (int m = 0; m < 4; ++m) {
        const unsigned short* ar =
            un + (size_t)(i0 + wr * 64 + m * 16 + lr) * DIM + lg * 8;
        #pragma unroll
        for (int k = 0; k < 8; ++k)
            av[m][k] = *(const short8*)(ar + k * 32);
    }

    // ---- stage one 64-row j-tile: instr (wid,s) fills kg=wid*8+s slab;
    //      lane l -> Bs[kg][l][0..7] <- vn[(jt+l)*256 + kg*8 ..] ----
    auto stage = [&](int buf, int jt) {
        #pragma unroll
        for (int s = 0; s < 8; ++s) {
            const int kg = wid * 8 + s;
            const unsigned short* src = vn + (size_t)(jt + lane) * DIM + kg * 8;
            __builtin_amdgcn_global_load_lds((g_void*)src,
                (l_void*)&Bs[buf][kg][0][0], 16, 0, 0);
        }
    };

    float rs[4][4] = {};

    stage(0, j0);
    __syncthreads();

    int buf = 0;
    for (int js = 0; js < 16; ++js) {
        if (js < 15) stage(buf ^ 1, j0 + (js + 1) * 64);

        f32x4 acc[4][2];
        #pragma unroll
        for (int k = 0; k < 8; ++k) {
            const short8 b0 = *(const short8*)&Bs[buf][k * 4 + lg][wc * 32 + lr][0];
            const short8 b1 = *(const short8*)&Bs[buf][k * 4 + lg][wc * 32 + 16 + lr][0];
            if (k == 0) {
                const f32x4 z = {0.f, 0.f, 0.f, 0.f};
                #pragma unroll
                for (int m = 0; m < 4; ++m) {
                    acc[m][0] = __builtin_amdgcn_mfma_f32_16x16x32_bf16(av[m][0], b0, z, 0, 0, 0);
                    acc[m][1] = __builtin_amdgcn_mfma_f32_16x16x32_bf16(av[m][0], b1, z, 0, 0, 0);
                }
            } else {
                #pragma unroll
                for (int m = 0; m < 4; ++m) {
                    acc[m][0] = __builtin_amdgcn_mfma_f32_16x16x32_bf16(av[m][k], b0, acc[m][0], 0, 0, 0);
                    acc[m][1] = __builtin_amdgcn_mfma_f32_16x16x32_bf16(av[m][k], b1, acc[m][1], 0, 0, 0);
                }
            }
        }

        #pragma unroll
        for (int m = 0; m < 4; ++m)
            #pragma unroll
            for (int n = 0; n < 2; ++n)
                #pragma unroll
                for (int r = 0; r < 4; ++r)
                    rs[m][r] += __expf(acc[m][n][r] * INV_T);

        __syncthreads();
        buf ^= 1;
    }

    // ---- per-row reduce across the 16 col-lanes; C/D row = lg*4 + r ----
    #pragma unroll
    for (int m = 0; m < 4; ++m)
        #pragma unroll
        for (int r = 0; r < 4; ++r) {
            float s = rs[m][r];
            s += __shfl_xor(s, 1);
            s += __shfl_xor(s, 2);
            s += __shfl_xor(s, 4);
            s += __shfl_xor(s, 8);
            if (lr == 0)
                atomicAdd(&rowsum[i0 + wr * 64 + m * 16 + lg * 4 + r], s);
        }
}

// ---------------------------------------------------------------------------
// Kernel 3 (single block): out = mean(log(rowsum) - diag). No memset needed.
// ---------------------------------------------------------------------------
__global__ __launch_bounds__(1024) void finish_kernel(
    const float* __restrict__ rowsum, const float* __restrict__ diag,
    float* __restrict__ out)
{
    __shared__ float red[16];
    const int t    = threadIdx.x;
    const int lane = t & 63;
    const int wid  = t >> 6;

    float c = 0.0f;
    #pragma unroll
    for (int q = 0; q < 8; ++q) {
        const int r = t + 1024 * q;
        c += logf(rowsum[r]) - diag[r];
    }
    #pragma unroll
    for (int m = 32; m >= 1; m >>= 1) c += __shfl_xor(c, m);
    if (lane == 0) red[wid] = c;
    __syncthreads();
    if (t == 0) {
        float s = 0.0f;
        #pragma unroll
        for (int k = 0; k < 16; ++k) s += red[k];
        out[0] = s * (1.0f / (float)NROWS);
    }
}

// ---------------------------------------------------------------------------
extern "C" void kernel_launch(void* const* d_in, const int* in_sizes, int n_in,
                              void* d_out, int out_size, void* d_ws, size_t ws_size,
                              hipStream_t stream)
{
    const float* u = (const float*)d_in[0];
    const float* v = (const float*)d_in[1];
    float* out = (float*)d_out;

    char* w = (char*)d_ws;
    unsigned short* un = (unsigned short*)w;                                  // 4 MB
    unsigned short* vn = (unsigned short*)(w + (size_t)NROWS * DIM * 2);      // 4 MB
    float* diag   = (float*)(w + (size_t)NROWS * DIM * 4);                    // 32 KB
    float* rowsum = diag + NROWS;                                             // 32 KB

    norm_kernel<<<NROWS / 4, 256, 0, stream>>>(u, v, un, vn, diag, rowsum);
    gemm_kernel<<<512, 256, 0, stream>>>(un, vn, rowsum);
    finish_kernel<<<1, 1024, 0, stream>>>(rowsum, diag, out);
}